// Round 1
// baseline (45.225 us; speedup 1.0000x reference)
//
#include <hip/hip_runtime.h>
#include <math.h>

// MXFP8_E4M3 quant-dequant, E8M0 shared scale, BLOCK=32, fp32 in/out.
//
// Exact-math formulation: scale = 2^S with S = floor(log2(amax)) - 3.
// Quant-dequant of x is snapping to ulp grid 2^g with
//   g = max(floor(log2|x|) - 3, S - 9)
// (S-9 encodes the E4M3 emin=-6 ulp clamp pulled back through the scale).
// rintf == round-half-to-even == jnp.round. ldexpf/frexpf are exact.
// E4M3 xmax=240 clip can never fire since |x/scale| < 16.

__device__ __forceinline__ float quant_elem(float x, int Sm9) {
    int e2;
    (void)frexpf(x, &e2);                 // |x| = m * 2^e2, m in [0.5,1); x==0 -> e2=0 (safe)
    int g = e2 - 4;                        // floor(log2|x|) - 3  (= e2 - 1 - 3)
    if (g < Sm9) g = Sm9;                  // emin clamp of E4M3 subnormal grid
    float r = rintf(ldexpf(x, -g));        // round-half-even on the 2^g grid
    return ldexpf(r, g);
}

__global__ __launch_bounds__(256) void mxq_kernel(const float* __restrict__ x,
                                                  float* __restrict__ out,
                                                  int n4) {
    const float INF = __builtin_huge_valf();
    int idx = blockIdx.x * blockDim.x + threadIdx.x;
    int stride = gridDim.x * blockDim.x;
    for (int i = idx; i < n4; i += stride) {
        float4 v = reinterpret_cast<const float4*>(x)[i];

        // per-thread amax of 4 elems; NaN -> Inf so invalid blocks are flagged
        // (fminf(NaN, INF) = INF; Inf stays Inf; finite stays finite)
        float a0 = fminf(fabsf(v.x), INF);
        float a1 = fminf(fabsf(v.y), INF);
        float a2 = fminf(fabsf(v.z), INF);
        float a3 = fminf(fabsf(v.w), INF);
        float m = fmaxf(fmaxf(a0, a1), fmaxf(a2, a3));

        // 8 consecutive lanes = one MX block of 32 elements.
        // xor masks 1,2,4 stay inside aligned 8-lane groups of the wave64.
        m = fmaxf(m, __shfl_xor(m, 1));
        m = fmaxf(m, __shfl_xor(m, 2));
        m = fmaxf(m, __shfl_xor(m, 4));

        bool valid = (m > 0.0f) && (m < INF);   // amax>0 && isfinite(amax)

        int e2m = 0;
        if (valid) (void)frexpf(m, &e2m);
        int S = e2m - 4;                        // floor(log2(amax)) - 3
        if (S < -127) valid = false;            // E8M0 chop -> scale 0 -> block zeros
        if (S == -127) S = -126;                // RN bumps to smallest normal

        float4 o;
        if (valid) {
            int Sm9 = S - 9;
            o.x = quant_elem(v.x, Sm9);
            o.y = quant_elem(v.y, Sm9);
            o.z = quant_elem(v.z, Sm9);
            o.w = quant_elem(v.w, Sm9);
        } else {
            o.x = 0.0f; o.y = 0.0f; o.z = 0.0f; o.w = 0.0f;
        }
        reinterpret_cast<float4*>(out)[i] = o;
    }
}

extern "C" void kernel_launch(void* const* d_in, const int* in_sizes, int n_in,
                              void* d_out, int out_size, void* d_ws, size_t ws_size,
                              hipStream_t stream) {
    const float* x = (const float*)d_in[0];
    float* out = (float*)d_out;
    int n = in_sizes[0];
    int n4 = n >> 2;                       // n = 4096*8192, divisible by 4
    int block = 256;
    int grid = (n4 + block - 1) / block;
    if (grid > 2048) grid = 2048;          // grid-stride; 8 blocks/CU on 256 CUs
    mxq_kernel<<<grid, block, 0, stream>>>(x, out, n4);
}